// Round 1
// baseline (486.620 us; speedup 1.0000x reference)
//
#include <hip/hip_runtime.h>

#define N_NODES 100000
#define N_EDGES 1250000
#define IN_F 128
#define OUT_F 64

// ---------------------------------------------------------------------------
// Kernel 1: h = x @ W   (f32, no MFMA on CDNA4 for fp32 — vector FMA)
// Block: 256 threads, 16 rows per block. W (128x64 = 32KB) + x tile (8KB) in LDS.
// Wave layout: lane = output col (0..63), rowgroup = wave id -> LDS x reads are
// lane-uniform (broadcast, conflict-free); W reads are stride-1 (2-way, free).
// ---------------------------------------------------------------------------
__global__ __launch_bounds__(256) void gemm_k(const float* __restrict__ x,
                                              const float* __restrict__ w,
                                              float* __restrict__ h) {
    __shared__ float wlds[IN_F * OUT_F];   // 32 KB
    __shared__ float xlds[16 * IN_F];      // 8 KB
    const int t = threadIdx.x;

    const float4* w4 = (const float4*)w;
    float4* wl4 = (float4*)wlds;
    #pragma unroll
    for (int i = t; i < IN_F * OUT_F / 4; i += 256) wl4[i] = w4[i];

    const long row0 = (long)blockIdx.x * 16;
    const float4* x4 = (const float4*)(x + row0 * IN_F);
    float4* xl4 = (float4*)xlds;
    #pragma unroll
    for (int i = t; i < 16 * IN_F / 4; i += 256) xl4[i] = x4[i];

    __syncthreads();

    const int col = t & 63;
    const int rg  = t >> 6;            // 0..3 -> rows rg*4 .. rg*4+3
    float acc0 = 0.f, acc1 = 0.f, acc2 = 0.f, acc3 = 0.f;

    #pragma unroll 8
    for (int k = 0; k < IN_F; ++k) {
        const float wv = wlds[k * OUT_F + col];
        acc0 += xlds[(rg * 4 + 0) * IN_F + k] * wv;
        acc1 += xlds[(rg * 4 + 1) * IN_F + k] * wv;
        acc2 += xlds[(rg * 4 + 2) * IN_F + k] * wv;
        acc3 += xlds[(rg * 4 + 3) * IN_F + k] * wv;
    }

    float* hp = h + (row0 + rg * 4) * OUT_F + col;
    hp[0 * OUT_F] = acc0;
    hp[1 * OUT_F] = acc1;
    hp[2 * OUT_F] = acc2;
    hp[3 * OUT_F] = acc3;
}

// ---------------------------------------------------------------------------
// Kernel 2: per-edge gather + scale + scatter-add (atomics).
// One wave (64 lanes) per edge; lane = feature. h[src] read is a coalesced
// 256B segment; scatter is 64 fp32 atomicAdds to out[dst]. Lane 0 counts.
// ---------------------------------------------------------------------------
__global__ __launch_bounds__(256) void scatter_k(const float* __restrict__ h,
                                                 const float* __restrict__ ew,
                                                 const int* __restrict__ src,
                                                 const int* __restrict__ dst,
                                                 float* __restrict__ out,
                                                 float* __restrict__ cnt) {
    const int e = blockIdx.x * 4 + (threadIdx.x >> 6);
    if (e >= N_EDGES) return;
    const int lane = threadIdx.x & 63;

    const int   s = src[e];
    const int   d = dst[e];
    const float w = ew[e];

    const float v = h[(long)s * OUT_F + lane] * w;
    atomicAdd(&out[(long)d * OUT_F + lane], v);
    if (lane == 0) atomicAdd(&cnt[d], 1.0f);
}

// ---------------------------------------------------------------------------
// Kernel 3: out = relu(out / max(cnt,1) + bias), in-place on d_out.
// ---------------------------------------------------------------------------
__global__ __launch_bounds__(256) void final_k(float* __restrict__ out,
                                               const float* __restrict__ cnt,
                                               const float* __restrict__ bias) {
    const int tid = blockIdx.x * 256 + threadIdx.x;
    if (tid >= N_NODES * OUT_F) return;
    const int n = tid >> 6;
    const int f = tid & 63;
    float c = cnt[n];
    if (c < 1.0f) c = 1.0f;
    float v = out[tid] / c + bias[f];
    out[tid] = v > 0.0f ? v : 0.0f;
}

extern "C" void kernel_launch(void* const* d_in, const int* in_sizes, int n_in,
                              void* d_out, int out_size, void* d_ws, size_t ws_size,
                              hipStream_t stream) {
    const float* x    = (const float*)d_in[0];   // [N_NODES, IN_F]
    const float* w    = (const float*)d_in[1];   // [IN_F, OUT_F]
    const float* bias = (const float*)d_in[2];   // [OUT_F]
    const float* ew   = (const float*)d_in[3];   // [N_EDGES]
    const int*   ei   = (const int*)d_in[4];     // [2, N_EDGES] (int32 per harness)

    float* out = (float*)d_out;                              // [N_NODES, OUT_F]
    float* h   = (float*)d_ws;                               // [N_NODES, OUT_F]
    float* cnt = (float*)((char*)d_ws + (size_t)N_NODES * OUT_F * sizeof(float));

    // Zero accumulators (d_out / d_ws are poisoned 0xAA before every launch).
    hipMemsetAsync(out, 0, (size_t)N_NODES * OUT_F * sizeof(float), stream);
    hipMemsetAsync(cnt, 0, (size_t)N_NODES * sizeof(float), stream);

    gemm_k<<<N_NODES / 16, 256, 0, stream>>>(x, w, h);                 // 6250 blocks
    scatter_k<<<(N_EDGES + 3) / 4, 256, 0, stream>>>(h, ew, ei, ei + N_EDGES, out, cnt);
    final_k<<<(N_NODES * OUT_F + 255) / 256, 256, 0, stream>>>(out, cnt, bias);
}

// Round 9
// 334.507 us; speedup vs baseline: 1.4547x; 1.4547x over previous
//
#include <hip/hip_runtime.h>

#define N_NODES 100000
#define N_EDGES 1250000
#define IN_F 128
#define OUT_F 64

// ---------------------------------------------------------------------------
// Kernel 1: h = x @ W  (fp32 vector FMA; no fp32 MFMA on CDNA4).
// 32 rows/block, 4 waves, wave owns 8 rows, lane = output col.
// x read from LDS via ds_read_b128 (4 k per instr, broadcast across lanes);
// W read via ds_read_b32 (stride-1 across lanes -> 2-way = free).
// ---------------------------------------------------------------------------
#define GR 32
__global__ __launch_bounds__(256) void gemm2_k(const float* __restrict__ x,
                                               const float* __restrict__ w,
                                               float* __restrict__ h) {
    __shared__ float wlds[IN_F * OUT_F];   // 32 KB
    __shared__ float xlds[GR * IN_F];      // 16 KB
    const int t = threadIdx.x;

    const float4* w4 = (const float4*)w;
    float4* wl4 = (float4*)wlds;
    #pragma unroll
    for (int i = t; i < IN_F * OUT_F / 4; i += 256) wl4[i] = w4[i];

    const long row0 = (long)blockIdx.x * GR;
    const float4* x4 = (const float4*)(x + row0 * IN_F);
    float4* xl4 = (float4*)xlds;
    #pragma unroll
    for (int i = t; i < GR * IN_F / 4; i += 256) xl4[i] = x4[i];

    __syncthreads();

    const int col = t & 63;
    const int wv  = t >> 6;                // wave id -> rows wv*8 .. wv*8+7
    float acc[8];
    #pragma unroll
    for (int r = 0; r < 8; ++r) acc[r] = 0.f;

    #pragma unroll
    for (int k = 0; k < IN_F; k += 4) {
        const float w0 = wlds[(k + 0) * OUT_F + col];
        const float w1 = wlds[(k + 1) * OUT_F + col];
        const float w2 = wlds[(k + 2) * OUT_F + col];
        const float w3 = wlds[(k + 3) * OUT_F + col];
        #pragma unroll
        for (int r = 0; r < 8; ++r) {
            const float4 xv = *(const float4*)&xlds[(wv * 8 + r) * IN_F + k];
            acc[r] += xv.x * w0 + xv.y * w1 + xv.z * w2 + xv.w * w3;
        }
    }

    #pragma unroll
    for (int r = 0; r < 8; ++r)
        h[(row0 + wv * 8 + r) * OUT_F + col] = acc[r];
}

// ---------------------------------------------------------------------------
// Counting sort of edges by dst: histogram -> 3-step exclusive scan -> bucket.
// ---------------------------------------------------------------------------
__global__ __launch_bounds__(256) void hist_k(const int* __restrict__ dst,
                                              int* __restrict__ cnt) {
    const int e = blockIdx.x * 256 + threadIdx.x;
    if (e >= N_EDGES) return;
    atomicAdd(&cnt[dst[e]], 1);
}

#define SCAN_B 1024   // elements per scan block (256 threads x 4)
__global__ __launch_bounds__(256) void scan1_k(const int* __restrict__ cnt,
                                               int* __restrict__ start,
                                               int* __restrict__ bsum) {
    __shared__ int lds[256];
    const int t = threadIdx.x;
    const int base = blockIdx.x * SCAN_B + t * 4;
    int v0 = 0, v1 = 0, v2 = 0, v3 = 0;
    if (base + 0 < N_NODES) v0 = cnt[base + 0];
    if (base + 1 < N_NODES) v1 = cnt[base + 1];
    if (base + 2 < N_NODES) v2 = cnt[base + 2];
    if (base + 3 < N_NODES) v3 = cnt[base + 3];
    const int s = v0 + v1 + v2 + v3;
    lds[t] = s;
    __syncthreads();
    #pragma unroll
    for (int off = 1; off < 256; off <<= 1) {
        const int add = (t >= off) ? lds[t - off] : 0;
        __syncthreads();
        lds[t] += add;
        __syncthreads();
    }
    const int excl = lds[t] - s;
    if (base + 0 < N_NODES) start[base + 0] = excl;
    if (base + 1 < N_NODES) start[base + 1] = excl + v0;
    if (base + 2 < N_NODES) start[base + 2] = excl + v0 + v1;
    if (base + 3 < N_NODES) start[base + 3] = excl + v0 + v1 + v2;
    if (t == 255) bsum[blockIdx.x] = lds[t];
}

#define NSCAN_BLOCKS ((N_NODES + SCAN_B - 1) / SCAN_B)   // 98
__global__ __launch_bounds__(128) void scan2_k(int* __restrict__ bsum) {
    __shared__ int lds[128];
    const int t = threadIdx.x;
    const int v = (t < NSCAN_BLOCKS) ? bsum[t] : 0;
    lds[t] = v;
    __syncthreads();
    #pragma unroll
    for (int off = 1; off < 128; off <<= 1) {
        const int add = (t >= off) ? lds[t - off] : 0;
        __syncthreads();
        lds[t] += add;
        __syncthreads();
    }
    if (t < NSCAN_BLOCKS) bsum[t] = lds[t] - v;   // exclusive
}

__global__ __launch_bounds__(256) void scan3_k(int* __restrict__ start,
                                               int* __restrict__ pos,
                                               const int* __restrict__ bsum) {
    const int i = blockIdx.x * 256 + threadIdx.x;
    if (i >= N_NODES) return;
    const int v = start[i] + bsum[i / SCAN_B];
    start[i] = v;
    pos[i] = v;
}

__global__ __launch_bounds__(256) void bucket_k(const int* __restrict__ src,
                                                const int* __restrict__ dst,
                                                const float* __restrict__ ew,
                                                int* __restrict__ pos,
                                                uint2* __restrict__ pairs) {
    const int e = blockIdx.x * 256 + threadIdx.x;
    if (e >= N_EDGES) return;
    const int d = dst[e];
    const int p = atomicAdd(&pos[d], 1);
    pairs[p] = make_uint2((unsigned)src[e], __float_as_uint(ew[e]));
}

// ---------------------------------------------------------------------------
// Kernel: per-node gather-accumulate + fused finalize (div/bias/relu).
// Quarter-wave per edge-slot: 16 lanes x float4 cover 64 feats; 4 edges in
// flight per wave; cross-quarter shfl_xor reduce; q==0 writes 256B/node.
// No atomics, writes exactly N_NODES*64 floats.
// ---------------------------------------------------------------------------
__global__ __launch_bounds__(256) void accum_k(const float* __restrict__ h,
                                               const uint2* __restrict__ pairs,
                                               const int* __restrict__ start,
                                               const int* __restrict__ cnt,
                                               const float* __restrict__ bias,
                                               float* __restrict__ out) {
    const int node = blockIdx.x * 4 + (threadIdx.x >> 6);
    const int lane = threadIdx.x & 63;
    const int q  = lane >> 4;
    const int ql = lane & 15;
    const int s0 = start[node];
    const int c  = cnt[node];

    float4 acc = make_float4(0.f, 0.f, 0.f, 0.f);
    for (int i = s0 + q; i < s0 + c; i += 4) {
        const uint2 pr = pairs[i];
        const float wgt = __uint_as_float(pr.y);
        const float4 hv = ((const float4*)(h + (size_t)pr.x * OUT_F))[ql];
        acc.x += hv.x * wgt;
        acc.y += hv.y * wgt;
        acc.z += hv.z * wgt;
        acc.w += hv.w * wgt;
    }

    #pragma unroll
    for (int m = 16; m <= 32; m <<= 1) {
        acc.x += __shfl_xor(acc.x, m, 64);
        acc.y += __shfl_xor(acc.y, m, 64);
        acc.z += __shfl_xor(acc.z, m, 64);
        acc.w += __shfl_xor(acc.w, m, 64);
    }

    if (q == 0) {
        float cf = (float)c;
        if (cf < 1.f) cf = 1.f;
        const float inv = 1.0f / cf;
        const float4 b = ((const float4*)bias)[ql];
        float4 v;
        v.x = acc.x * inv + b.x;
        v.y = acc.y * inv + b.y;
        v.z = acc.z * inv + b.z;
        v.w = acc.w * inv + b.w;
        v.x = v.x > 0.f ? v.x : 0.f;
        v.y = v.y > 0.f ? v.y : 0.f;
        v.z = v.z > 0.f ? v.z : 0.f;
        v.w = v.w > 0.f ? v.w : 0.f;
        ((float4*)(out + (size_t)node * OUT_F))[ql] = v;
    }
}

// ---------------------------------------------------------------------------
// Fallback path (round-1 proven): atomic scatter + finalize. Used only if
// ws_size is too small for the sort path (needs just h + cnt = 26 MB).
// ---------------------------------------------------------------------------
__global__ __launch_bounds__(256) void scatter_k(const float* __restrict__ h,
                                                 const float* __restrict__ ew,
                                                 const int* __restrict__ src,
                                                 const int* __restrict__ dst,
                                                 float* __restrict__ out,
                                                 float* __restrict__ cnt) {
    const int e = blockIdx.x * 4 + (threadIdx.x >> 6);
    if (e >= N_EDGES) return;
    const int lane = threadIdx.x & 63;
    const int   s = src[e];
    const int   d = dst[e];
    const float w = ew[e];
    const float v = h[(long)s * OUT_F + lane] * w;
    atomicAdd(&out[(long)d * OUT_F + lane], v);
    if (lane == 0) atomicAdd(&cnt[d], 1.0f);
}

__global__ __launch_bounds__(256) void final_k(float* __restrict__ out,
                                               const float* __restrict__ cnt,
                                               const float* __restrict__ bias) {
    const int tid = blockIdx.x * 256 + threadIdx.x;
    if (tid >= N_NODES * OUT_F) return;
    const int n = tid >> 6;
    const int f = tid & 63;
    float c = cnt[n];
    if (c < 1.0f) c = 1.0f;
    float v = out[tid] / c + bias[f];
    out[tid] = v > 0.0f ? v : 0.0f;
}

extern "C" void kernel_launch(void* const* d_in, const int* in_sizes, int n_in,
                              void* d_out, int out_size, void* d_ws, size_t ws_size,
                              hipStream_t stream) {
    const float* x    = (const float*)d_in[0];   // [N_NODES, IN_F]
    const float* w    = (const float*)d_in[1];   // [IN_F, OUT_F]
    const float* bias = (const float*)d_in[2];   // [OUT_F]
    const float* ew   = (const float*)d_in[3];   // [N_EDGES]
    const int*   ei   = (const int*)d_in[4];     // [2, N_EDGES] as int32

    float* out = (float*)d_out;
    const int* src = ei;
    const int* dst = ei + N_EDGES;

    // Workspace layout (bytes):
    char* ws = (char*)d_ws;
    float* h     = (float*)(ws);                                   // 25.6 MB
    int*   cnt   = (int*)(ws + 25600000);                          // 400 KB
    int*   start = (int*)(ws + 26000000);                          // 400 KB
    int*   pos   = (int*)(ws + 26400000);                          // 400 KB
    int*   bsum  = (int*)(ws + 26800000);                          // 1 KB
    uint2* pairs = (uint2*)(ws + 26801024);                        // 10 MB
    const size_t WS_NEEDED = 26801024 + (size_t)N_EDGES * sizeof(uint2);

    gemm2_k<<<N_NODES / GR, 256, 0, stream>>>(x, w, h);                       // 3125

    if (ws_size >= WS_NEEDED) {
        // Sorted gather path: no output atomics.
        hipMemsetAsync(cnt, 0, N_NODES * sizeof(int), stream);
        hist_k<<<(N_EDGES + 255) / 256, 256, 0, stream>>>(dst, cnt);          // 4883
        scan1_k<<<NSCAN_BLOCKS, 256, 0, stream>>>(cnt, start, bsum);          // 98
        scan2_k<<<1, 128, 0, stream>>>(bsum);
        scan3_k<<<(N_NODES + 255) / 256, 256, 0, stream>>>(start, pos, bsum); // 391
        bucket_k<<<(N_EDGES + 255) / 256, 256, 0, stream>>>(src, dst, ew, pos, pairs);
        accum_k<<<N_NODES / 4, 256, 0, stream>>>(h, pairs, start, cnt, bias, out);
    } else {
        // Fallback: atomic scatter (round-1 proven, 26 MB workspace).
        float* fcnt = (float*)cnt;
        hipMemsetAsync(out, 0, (size_t)N_NODES * OUT_F * sizeof(float), stream);
        hipMemsetAsync(fcnt, 0, N_NODES * sizeof(float), stream);
        scatter_k<<<(N_EDGES + 3) / 4, 256, 0, stream>>>(h, ew, src, dst, out, fcnt);
        final_k<<<(N_NODES * OUT_F + 255) / 256, 256, 0, stream>>>(out, fcnt, bias);
    }
}